// Round 2
// baseline (1583.207 us; speedup 1.0000x reference)
//
#include <hip/hip_runtime.h>

typedef unsigned short u16;
typedef unsigned int u32;
typedef unsigned long long u64;
typedef __attribute__((ext_vector_type(8))) short bf16x8;
typedef __attribute__((ext_vector_type(4))) float f32x4;
typedef __attribute__((ext_vector_type(4))) unsigned short us4;

#define MFMA(a,b,c) __builtin_amdgcn_mfma_f32_16x16x32_bf16((a),(b),(c),0,0,0)
#define KEEP(x) asm volatile("" : "+v"(x))

// B=128, SEQ=200, VOCAB=1400 (pad 1408), D=H=256, 4H=1024, NCLS=128, M=B*SEQ=25600

static __device__ __forceinline__ u16 f2b(float f){
  unsigned u = __float_as_uint(f);
  u += 0x7fffu + ((u >> 16) & 1u);          // RNE fp32 -> bf16
  return (u16)(u >> 16);
}
static __device__ __forceinline__ float sigm(float x){ return 1.0f/(1.0f+__expf(-x)); }
static __device__ __forceinline__ float tanhx(float x){
  x = fminf(fmaxf(x, -15.f), 15.f);
  float e = __expf(-2.f*x);
  return (1.f - e)/(1.f + e);
}
static __device__ __forceinline__ void gl16(const void* g, void* l){
  __builtin_amdgcn_global_load_lds((const __attribute__((address_space(1))) void*)g,
                                   (__attribute__((address_space(3))) void*)l, 16, 0, 0);
}

// ---------------- fused prep: inputs cvt + emb transpose-cvt + weights ----
__global__ __launch_bounds__(256) void k_prep(
  const float* __restrict__ in0, u16* __restrict__ A0,
  const float* __restrict__ emb, u16* __restrict__ embT,
  const float* __restrict__ s0, const float* __restrict__ s1, const float* __restrict__ s2,
  const float* __restrict__ s3, const float* __restrict__ s4, const float* __restrict__ s5,
  const float* __restrict__ s6,
  u16* __restrict__ d0, u16* __restrict__ d1, u16* __restrict__ d2, u16* __restrict__ d3,
  u16* __restrict__ d4, u16* __restrict__ d5, u16* __restrict__ d6)
{
  int bx = blockIdx.x, tid = threadIdx.x;
  if (bx < 35200){                     // inputs [25600 x 1400] -> bf16 padded 1408
    long long i4 = (long long)bx*256 + tid;      // < 9011200 exactly
    long long o = i4*4;
    int r = (int)(o / 1408);
    int c = (int)(o % 1408);
    us4 d;
    if (c + 4 <= 1400){
      f32x4 v = *(const f32x4*)&in0[(long long)r*1400 + c];
      d[0]=f2b(v[0]); d[1]=f2b(v[1]); d[2]=f2b(v[2]); d[3]=f2b(v[3]);
    } else {
      for (int k=0;k<4;k++){ int cc=c+k; d[k] = (cc<1400)? f2b(in0[(long long)r*1400+cc]) : (u16)0; }
    }
    *(us4*)&A0[(long long)r*1408 + c] = d;
  } else if (bx < 36608){              // emb [1400x256] -> embT [256x1408] bf16
    int idx = (bx-35200)*256 + tid;    // < 360448 exactly
    int n = idx / 1408, k = idx % 1408;
    embT[idx] = (k < 1400) ? f2b(emb[(long long)k*256 + n]) : (u16)0;
  } else {                             // 7 weight arrays fp32 -> bf16
    long long q = (long long)(bx-36608)*256 + tid;   // < 311296 exactly
    const float* src; u16* dst; long long rel;
    if      (q < 65536)  { src=s0; dst=d0; rel=q; }
    else if (q < 131072) { src=s1; dst=d1; rel=q-65536; }
    else if (q < 196608) { src=s2; dst=d2; rel=q-131072; }
    else if (q < 262144) { src=s3; dst=d3; rel=q-196608; }
    else if (q < 278528) { src=s4; dst=d4; rel=q-262144; }
    else if (q < 294912) { src=s5; dst=d5; rel=q-278528; }
    else                 { src=s6; dst=d6; rel=q-294912; }
    long long o = rel*4;
    f32x4 v = *(const f32x4*)&src[o];
    us4 d; d[0]=f2b(v[0]); d[1]=f2b(v[1]); d[2]=f2b(v[2]); d[3]=f2b(v[3]);
    *(us4*)&dst[o] = d;
  }
}

// ---------------- init: zero E + ctx + wave-flags ------------------------
__global__ __launch_bounds__(256) void k_init(float* __restrict__ E, float* __restrict__ ctx,
                                              int* __restrict__ fl){
  int i = blockIdx.x*256 + threadIdx.x;     // 229*256 = 58624
  if (i < 25600) E[i] = 0.f;
  else if (i < 58368) ctx[i-25600] = 0.f;   // 32768
  else if (i < 58496) fl[i-58368] = 0;      // 128 wave-flags (poll uses unsigned >=)
}

// ---------------- bf16 MFMA GEMM: C[M,N] = A[M,K] * Bt[N,K]^T -------------
// EPI 1: write fp32 + bf16 copies
// EPI 4: dual-output ux GEMM, +bias pair, fp32 (blockIdx.y>=8 -> second set)
// EPI 5: ctx[b,col] += emb[row,col]*tanh(acc)*alpha[row]  (LDS + global atomics)
template<int EPI>
__global__ __launch_bounds__(256) void k_gemm(const u16* __restrict__ A, const u16* __restrict__ Bt,
    int N, int K,
    float* __restrict__ Cf, u16* __restrict__ Cb,
    const float* __restrict__ bias1, const float* __restrict__ bias2,
    const u16* __restrict__ Bt2, float* __restrict__ Cf2,
    const float* __restrict__ bias3, const float* __restrict__ bias4,
    const float* __restrict__ emb, const float* __restrict__ alpha)
{
  __shared__ __align__(16) u16 As[128*64];
  __shared__ __align__(16) u16 Bs[128*64];
  __shared__ float red[2][128];
  const int tid = threadIdx.x;
  const int l = tid & 63, w = tid >> 6;
  const int quad = l >> 4, lb = l & 15;
  const int wr = w >> 1, wc = w & 1;
  const long long m0 = (long long)blockIdx.x * 128;
  int n0 = blockIdx.y * 128;
  if (EPI==4 && blockIdx.y >= 8){
    Bt = Bt2; Cf = Cf2; bias1 = bias3; bias2 = bias4; n0 = (blockIdx.y-8)*128;
  }

  f32x4 acc[4][4];
  #pragma unroll
  for (int i=0;i<4;i++)
    #pragma unroll
    for (int j=0;j<4;j++) acc[i][j] = (f32x4){0.f,0.f,0.f,0.f};

  for (int kk = 0; kk < K; kk += 64){
    #pragma unroll
    for (int it=0; it<4; ++it){      // 128x64 bf16 tile, XOR-swizzled 16B slots
      int slot = it*256 + tid;
      int m = slot >> 3;
      int q = (slot & 7) ^ (m & 7);
      gl16(A + (m0+m)*K + kk + q*8, &As[slot*8]);
    }
    #pragma unroll
    for (int it=0; it<4; ++it){
      int slot = it*256 + tid;
      int m = slot >> 3;
      int q = (slot & 7) ^ (m & 7);
      gl16(Bt + (long long)(n0+m)*K + kk + q*8, &Bs[slot*8]);
    }
    __syncthreads();
    #pragma unroll
    for (int ks=0; ks<2; ++ks){
      int kq = quad + ks*4;
      bf16x8 af[4], bfr[4];
      #pragma unroll
      for (int i=0;i<4;i++){ int m = wr*64 + i*16 + lb; af[i]  = *(const bf16x8*)&As[m*64 + ((kq ^ (m&7))*8)]; }
      #pragma unroll
      for (int j=0;j<4;j++){ int n = wc*64 + j*16 + lb; bfr[j] = *(const bf16x8*)&Bs[n*64 + ((kq ^ (n&7))*8)]; }
      #pragma unroll
      for (int i=0;i<4;i++)
        #pragma unroll
        for (int j=0;j<4;j++)
          acc[i][j] = MFMA(af[i], bfr[j], acc[i][j]);
    }
    __syncthreads();
  }

  if (EPI==5){
    const int b0 = (int)(m0 / 200);
    red[tid>>7][tid&127] = 0.f;
    __syncthreads();
    #pragma unroll
    for (int i=0;i<4;i++){
      #pragma unroll
      for (int j=0;j<4;j++){
        int col = wc*64 + j*16 + lb;          // 0..127 within n0 tile
        #pragma unroll
        for (int r=0;r<4;r++){
          long long row = m0 + wr*64 + i*16 + quad*4 + r;
          long long o = row*N + n0 + col;
          float v = emb[o] * tanhx(acc[i][j][r]) * alpha[row];
          atomicAdd(&red[(int)(row/200) - b0][col], v);
        }
      }
    }
    __syncthreads();
    int bl = tid >> 7, col = tid & 127;       // 256 threads cover [2][128]
    int bb = b0 + bl;
    if (bb < 128) atomicAdd(&Cf[bb*256 + n0 + col], red[bl][col]);
    return;
  }

  #pragma unroll
  for (int i=0;i<4;i++){
    #pragma unroll
    for (int j=0;j<4;j++){
      int col = n0 + wc*64 + j*16 + lb;
      #pragma unroll
      for (int r=0;r<4;r++){
        long long row = m0 + wr*64 + i*16 + quad*4 + r;
        long long o = row*N + col;
        float v = acc[i][j][r];
        if (EPI==1){ Cf[o]=v; Cb[o]=f2b(v); }
        else { Cf[o] = v + bias1[col] + bias2[col]; }   // EPI 4
      }
    }
  }
}

// ---------------- persistent TimeLSTM scan, 2-way j-split -----------------
// 32 WGs: jw = bi>>4 (j-half of 128), grp = bi&15 (lstm=(bi>>3)&1, bc=bi&7).
// Sibling WG = bi^16 (same bi%8 => same XCD under round-robin; speed-only).
// Wall slice (4g x 128j x 256k bf16, 256 regs/lane) register/AGPR-resident;
// Wd slice (128j x 256k, 64KB) in LDS, slot-XOR-swizzled for conflict-free
// ds_read_b128 A-frags.
//
// Exchange (per-wave flag protocol, r0-proven visibility argument):
//  elementwise -> issue 8x8B relaxed agent data stores (dense, untagged)
//  -> raw s_barrier B1 (orders step-s LDS reads vs h/c overwrites)
//  -> own-half LDS writes -> wave-local s_waitcnt vmcnt(0) (store ack)
//  -> lane0 publishes THIS WAVE's flag = s+1 (flag after drain => data
//     visible before flag; reader's chunk maps to exactly one writer wave)
//  -> E/out2 + next-step ux prefetch (off the drain path)
//  -> poll ONE 4B flag word (cheap spin) -> 2x16B data loads -> LDS write
//  -> B2 (lgkmcnt only; vmcnt stays in flight).
// Slot-parity double buffer; mutual-dependence induction bounds skew to 1
// step => no overwrite race. Flags monotonic 1..199, zeroed by k_init, so
// unsigned >= poll is deadlock-free.
__global__ __launch_bounds__(256,1) void k_scan(
  const u16* __restrict__ Wall1, const u16* __restrict__ Wd1, const float* __restrict__ Wd1b,
  const float* __restrict__ ux1, const float* __restrict__ h01, const float* __restrict__ c01,
  const u16* __restrict__ Wall2, const u16* __restrict__ Wd2, const float* __restrict__ Wd2b,
  const float* __restrict__ ux2, const float* __restrict__ h02, const float* __restrict__ c02,
  const float* __restrict__ ts, const float* __restrict__ wa,
  float* __restrict__ E, u16* __restrict__ out2,
  u64* __restrict__ hx, u64* __restrict__ cx, int* __restrict__ fl)
{
  __shared__ __align__(16) u16 hb[16][264];
  __shared__ __align__(16) u16 cb[16][264];
  __shared__ __align__(16) u16 wdl[128*256];     // 64KB swizzled Wd slice
  const int bi = blockIdx.x;
  const int jw   = bi >> 4;            // j-half 0/1
  const int grp  = bi & 15;
  const int lstm = (bi >> 3) & 1;
  const int bc   = bi & 7;
  const u16* Wall  = lstm ? Wall2 : Wall1;
  const u16* Wd    = lstm ? Wd2   : Wd1;
  const float* Wdb = lstm ? Wd2b  : Wd1b;
  const float* ux  = lstm ? ux2   : ux1;
  const float* h0  = lstm ? h02   : h01;
  const float* c0  = lstm ? c02   : c01;

  const int tid = threadIdx.x;
  const int l = tid & 63, w = tid >> 6;
  const int quad = l >> 4, lb = l & 15;
  const int bg = bc*16 + lb;            // lane's global batch
  const int J = jw*128;                 // own j-half base
  const int Js = (jw^1)*128;            // sibling j-half base
  const int jrow = w*32;                // wave's 32-row band within half
  const int jl0 = J + jrow + quad*4;    // lane's j rows (tile t adds t*16)
  // reader role: thread (bb,jj) refills sibling batch bb, j chunk [jj*8,jj*8+8)
  const int bb = tid >> 4, jj = tid & 15, j0 = jj*8;
  const int wsib = jj >> 2;             // sibling wave owning that chunk

  // ---- one-time: Wall fragments into registers (A-frag: row=..+lb, k=quad*8)
  bf16x8 wfA[4][2][8];
  #pragma unroll
  for (int g=0; g<4; ++g)
    #pragma unroll
    for (int t=0; t<2; ++t)
      #pragma unroll
      for (int kk=0; kk<8; ++kk){
        wfA[g][t][kk] = *(const bf16x8*)&Wall[(long long)(g*256 + J + jrow + t*16 + lb)*256 + kk*32 + quad*8];
        KEEP(wfA[g][t][kk]);
      }
  // ---- one-time: Wd slice -> LDS, 16B-slot XOR swizzle (slot ^= row&7)
  for (int it=0; it<16; ++it){
    int idx = it*256 + tid;             // 4096 slots of 16B
    int rho = idx >> 5, sl = idx & 31;
    bf16x8 v = *(const bf16x8*)&Wd[(long long)(J + rho)*256 + sl*8];
    *(bf16x8*)&wdl[rho*256 + ((sl ^ (rho & 7))<<3)] = v;
  }

  f32x4 bcs[2], wav2[2], creg[2];
  #pragma unroll
  for (int t=0;t<2;++t){
    bcs[t]  = *(const f32x4*)&Wdb[jl0 + t*16];
    wav2[t] = *(const f32x4*)&wa[jl0 + t*16];
    creg[t] = *(const f32x4*)&c0[(long long)bg*256 + jl0 + t*16];
  }

  // ---- init LDS h/c (full 256 j for our 16 batches), bf16
  {
    int j0i = (tid & 15) * 16;
    #pragma unroll
    for (int kq=0; kq<4; ++kq){
      f32x4 hv = *(const f32x4*)&h0[(long long)(bc*16+bb)*256 + j0i + kq*4];
      f32x4 cv = *(const f32x4*)&c0[(long long)(bc*16+bb)*256 + j0i + kq*4];
      us4 hp0, cp0;
      #pragma unroll
      for (int r=0;r<4;++r){ hp0[r]=f2b(hv[r]); cp0[r]=f2b(cv[r]); }
      *(us4*)&hb[bb][j0i+kq*4] = hp0;
      *(us4*)&cb[bb][j0i+kq*4] = cp0;
    }
  }
  __syncthreads();

  f32x4 uxr[4][2];
  #pragma unroll
  for (int g=0; g<4; ++g)
    #pragma unroll
    for (int t=0; t<2; ++t)
      uxr[g][t] = *(const f32x4*)&ux[(long long)bg*200*1024 + g*256 + jl0 + t*16];
  float tcur = ts[(long long)bg*200];

  for (int s=0; s<200; ++s){
    // c_s1 pre-act: Wd GEMV over cb (weights from swizzled LDS)
    f32x4 ad[2] = { bcs[0], bcs[1] };
    #pragma unroll
    for (int kk=0;kk<8;++kk){
      bf16x8 cf = *(const bf16x8*)&cb[lb][kk*32 + quad*8];
      #pragma unroll
      for (int t=0;t<2;++t){
        bf16x8 wf = *(const bf16x8*)&wdl[(jrow + t*16 + lb)*256 + (((kk*4+quad) ^ (lb&7))<<3)];
        ad[t] = MFMA(wf, cf, ad[t]);
      }
    }
    // gates: ux + Wall GEMV over hb
    f32x4 ag[4][2];
    #pragma unroll
    for (int g=0; g<4; ++g)
      #pragma unroll
      for (int t=0; t<2; ++t) ag[g][t] = uxr[g][t];
    #pragma unroll
    for (int kk=0;kk<8;++kk){
      bf16x8 hf = *(const bf16x8*)&hb[lb][kk*32 + quad*8];
      #pragma unroll
      for (int g=0; g<4; ++g)
        #pragma unroll
        for (int t=0; t<2; ++t)
          ag[g][t] = MFMA(wfA[g][t][kk], hf, ag[g][t]);
    }
    // elementwise update (fp32 c carried in regs)
    f32x4 hn[2]; us4 hp[2], cp[2];
    #pragma unroll
    for (int t=0;t<2;++t){
      #pragma unroll
      for (int r=0;r<4;++r){
        float cs1 = tanhx(ad[t][r]);
        float cadj = creg[t][r] + cs1*(tcur - 1.0f);
        float fg = sigm(ag[0][t][r]);
        float ig = sigm(ag[1][t][r]);
        float og = sigm(ag[2][t][r]);
        float cg = sigm(ag[3][t][r]);
        float cn = fg*cadj + ig*cg;
        float hv = og*tanhx(cn);
        creg[t][r]=cn; hn[t][r]=hv;
        hp[t][r]=f2b(hv); cp[t][r]=f2b(cn);
      }
    }

    if (s < 199){
      const int slot = (s+1)&1;
      // dense untagged mailbox stores: 4x8B (h t0,t1 + c t0,t1)
      const int hxi = (grp*2 + slot)*2 + jw;
      long long xb = ((long long)hxi*16 + lb)*32 + w*8 + quad;
      u64 hq0, hq1, cq0, cq1;
      __builtin_memcpy(&hq0,&hp[0],8); __builtin_memcpy(&hq1,&hp[1],8);
      __builtin_memcpy(&cq0,&cp[0],8); __builtin_memcpy(&cq1,&cp[1],8);
      __hip_atomic_store(&hx[xb],     hq0, __ATOMIC_RELAXED, __HIP_MEMORY_SCOPE_AGENT);
      __hip_atomic_store(&hx[xb + 4], hq1, __ATOMIC_RELAXED, __HIP_MEMORY_SCOPE_AGENT);
      __hip_atomic_store(&cx[xb],     cq0, __ATOMIC_RELAXED, __HIP_MEMORY_SCOPE_AGENT);
      __hip_atomic_store(&cx[xb + 4], cq1, __ATOMIC_RELAXED, __HIP_MEMORY_SCOPE_AGENT);
      // B1: raw barrier — step-s LDS reads complete (operands latched) before
      // any wave overwrites hb/cb; no vmcnt drain here.
      asm volatile("" ::: "memory");
      __builtin_amdgcn_s_barrier();
      asm volatile("" ::: "memory");
      // own half: registers -> LDS
      *(us4*)&hb[lb][jl0]      = hp[0];
      *(us4*)&hb[lb][jl0 + 16] = hp[1];
      *(us4*)&cb[lb][jl0]      = cp[0];
      *(us4*)&cb[lb][jl0 + 16] = cp[1];
      // wave-local drain of the mailbox stores, then publish THIS wave's flag
      asm volatile("s_waitcnt vmcnt(0)" ::: "memory");
      if (l == 0)
        __hip_atomic_store(&fl[(grp*2 + jw)*4 + w], s+1, __ATOMIC_RELAXED, __HIP_MEMORY_SCOPE_AGENT);
      // outputs + next-step ux/ts prefetch: off the drain path, latency hides
      // under poll + B2 + next GEMV
      if (lstm==0){
        float e = hn[0][0]*wav2[0][0] + hn[0][1]*wav2[0][1] + hn[0][2]*wav2[0][2] + hn[0][3]*wav2[0][3]
                + hn[1][0]*wav2[1][0] + hn[1][1]*wav2[1][1] + hn[1][2]*wav2[1][2] + hn[1][3]*wav2[1][3];
        e += __shfl_xor(e, 16, 64);
        e += __shfl_xor(e, 32, 64);
        if (l < 16) atomicAdd(&E[(long long)bg*200 + s], e);
      } else {
        *(us4*)&out2[((long long)bg*200 + s)*256 + jl0]      = hp[0];
        *(us4*)&out2[((long long)bg*200 + s)*256 + jl0 + 16] = hp[1];
      }
      #pragma unroll
      for (int g=0; g<4; ++g)
        #pragma unroll
        for (int t=0; t<2; ++t)
          uxr[g][t] = *(const f32x4*)&ux[((long long)bg*200 + s+1)*1024 + g*256 + jl0 + t*16];
      tcur = ts[(long long)bg*200 + s+1];
      // poll ONE flag word (the writer wave owning my chunk), then dense loads
      {
        const int* sp = &fl[(grp*2 + (jw^1))*4 + wsib];
        while ((u32)__hip_atomic_load(sp, __ATOMIC_RELAXED, __HIP_MEMORY_SCOPE_AGENT) < (u32)(s+1))
          __builtin_amdgcn_s_sleep(1);
        long long rb = ((long long)((grp*2 + slot)*2 + (jw^1))*16 + bb)*32 + jj*2;
        u64 h0v = __hip_atomic_load(&hx[rb],   __ATOMIC_RELAXED, __HIP_MEMORY_SCOPE_AGENT);
        u64 h1v = __hip_atomic_load(&hx[rb+1], __ATOMIC_RELAXED, __HIP_MEMORY_SCOPE_AGENT);
        u64 c0v = __hip_atomic_load(&cx[rb],   __ATOMIC_RELAXED, __HIP_MEMORY_SCOPE_AGENT);
        u64 c1v = __hip_atomic_load(&cx[rb+1], __ATOMIC_RELAXED, __HIP_MEMORY_SCOPE_AGENT);
        *(u64*)&hb[bb][Js + j0]     = h0v;
        *(u64*)&hb[bb][Js + j0 + 4] = h1v;
        *(u64*)&cb[bb][Js + j0]     = c0v;
        *(u64*)&cb[bb][Js + j0 + 4] = c1v;
      }
      // B2: LDS h/c(s+1) complete; only lgkmcnt, vmcnt stays in flight
      asm volatile("s_waitcnt lgkmcnt(0)" ::: "memory");
      __builtin_amdgcn_sched_barrier(0);
      __builtin_amdgcn_s_barrier();
      asm volatile("" ::: "memory");
    } else {
      // final step: outputs only
      if (lstm==0){
        float e = hn[0][0]*wav2[0][0] + hn[0][1]*wav2[0][1] + hn[0][2]*wav2[0][2] + hn[0][3]*wav2[0][3]
                + hn[1][0]*wav2[1][0] + hn[1][1]*wav2[1][1] + hn[1][2]*wav2[1][2] + hn[1][3]*wav2[1][3];
        e += __shfl_xor(e, 16, 64);
        e += __shfl_xor(e, 32, 64);
        if (l < 16) atomicAdd(&E[(long long)bg*200 + s], e);
      } else {
        *(us4*)&out2[((long long)bg*200 + s)*256 + jl0]      = hp[0];
        *(us4*)&out2[((long long)bg*200 + s)*256 + jl0 + 16] = hp[1];
      }
    }
  }
}

// ---------------- softmax over precomputed E -> alpha ----------------
__global__ __launch_bounds__(256) void k_attn(const float* __restrict__ E, float* __restrict__ alpha){
  __shared__ float buf[256];
  int b = blockIdx.x, tid = threadIdx.x;
  float Ev = (tid < 200) ? E[(long long)b*200 + tid] : -1e30f;
  buf[tid]=Ev; __syncthreads();
  for (int st=128; st>0; st>>=1){ if (tid<st) buf[tid]=fmaxf(buf[tid],buf[tid+st]); __syncthreads(); }
  float mx = buf[0]; __syncthreads();
  float e = (tid<200)? __expf(Ev-mx) : 0.f;
  buf[tid]=e; __syncthreads();
  for (int st=128; st>0; st>>=1){ if (tid<st) buf[tid]+=buf[tid+st]; __syncthreads(); }
  float sm = buf[0];
  if (tid<200) alpha[(long long)b*200+tid] = e/sm;
}

// ---------------- out = ctx @ Wout^T ----------------
__global__ __launch_bounds__(128) void k_out(const float* __restrict__ ctx, const float* __restrict__ Wout,
                                             float* __restrict__ out){
  __shared__ float cs[256];
  int b = blockIdx.x, t = threadIdx.x;
  cs[t] = ctx[b*256+t]; cs[t+128] = ctx[b*256+t+128];
  __syncthreads();
  const float* wr = Wout + (long long)t*256;
  float a0=0,a1=0,a2=0,a3=0;
  for (int j=0;j<256;j+=4){
    f32x4 v = *(const f32x4*)&wr[j];
    a0+=v[0]*cs[j]; a1+=v[1]*cs[j+1]; a2+=v[2]*cs[j+2]; a3+=v[3]*cs[j+3];
  }
  out[(long long)b*128 + t] = (a0+a1)+(a2+a3);
}

extern "C" void kernel_launch(void* const* d_in, const int* in_sizes, int n_in,
                              void* d_out, int out_size, void* d_ws, size_t ws_size,
                              hipStream_t stream)
{
  (void)in_sizes; (void)n_in; (void)out_size; (void)ws_size;
  const float* inputs = (const float*)d_in[0];
  const float* tstamp = (const float*)d_in[1];
  const float* emb    = (const float*)d_in[2];
  const float* Wall1w = (const float*)d_in[3];
  const float* Wall1b = (const float*)d_in[4];
  const float* Uall1w = (const float*)d_in[5];
  const float* Uall1b = (const float*)d_in[6];
  const float* Wd1w   = (const float*)d_in[7];
  const float* Wd1b   = (const float*)d_in[8];
  const float* Wall2w = (const float*)d_in[9];
  const float* Wall2b = (const float*)d_in[10];
  const float* Uall2w = (const float*)d_in[11];
  const float* Uall2b = (const float*)d_in[12];
  const float* Wd2w   = (const float*)d_in[13];
  const float* Wd2b   = (const float*)d_in[14];
  const float* wa     = (const float*)d_in[15];
  const float* Wbw    = (const float*)d_in[16];
  const float* Woutw  = (const float*)d_in[17];
  const float* h01    = (const float*)d_in[18];
  const float* c01    = (const float*)d_in[19];
  const float* h02    = (const float*)d_in[20];
  const float* c02    = (const float*)d_in[21];

  char* ws = (char*)d_ws;
  float* ux1   = (float*)(ws + 0);              // 104857600
  float* ux2   = (float*)(ws + 104857600LL);
  float* embF  = (float*)(ws + 209715200LL);    // 26214400
  u16*   embB  = (u16*)  (ws + 235929600LL);    // 13107200
  char*  scr   =          ws + 249036800LL;     // 72089600 region
  u16*   A0    = (u16*)scr;                     // 72089600 (dead after embed GEMM)
  u16*   out2  = (u16*)  (scr + 0);             // 13107200
  float* alpha = (float*)(scr + 39321600LL);    // 102400
  float* ctx   = (float*)(scr + 39424000LL);    // 131072
  float* E     = (float*)(scr + 39555072LL);    // 102400
  u64*   hx    = (u64*)  (scr + 39657472LL);    // 262144 (2 slots x 16 grp x 2 jw x 16 b x 32 u64)
  u64*   cx    = (u64*)  (scr + 40181760LL);    // 262144
  int*   fl    = (int*)  (scr + 40706048LL);    // 512 (128 wave-flags)
  u16* embT    = (u16*)(ws + 321126400LL);      // 720896
  u16* Wall1B  = (u16*)(ws + 321847296LL);      // 524288
  u16* Wall2B  = (u16*)(ws + 322371584LL);
  u16* Uall1B  = (u16*)(ws + 322895872LL);
  u16* Uall2B  = (u16*)(ws + 323420160LL);
  u16* Wd1B    = (u16*)(ws + 323944448LL);      // 131072
  u16* Wd2B    = (u16*)(ws + 324075520LL);
  u16* WbB     = (u16*)(ws + 324206592LL);
  // total ws: ~324.3 MB (same layout envelope as passing round)

  // 1) all conversions (inputs, emb^T, 7 weights) in one launch
  k_prep<<<37824, 256, 0, stream>>>(inputs, A0, emb, embT,
                                    Wall1w, Wall2w, Uall1w, Uall2w, Wd1w, Wd2w, Wbw,
                                    Wall1B, Wall2B, Uall1B, Uall2B, Wd1B, Wd2B, WbB);
  // 2) embedded = inputs @ emb  (fp32 + bf16 copies)
  k_gemm<1><<<dim3(200,2), 256, 0, stream>>>(A0, embT, 256, 1408, embF, embB,
                                             nullptr, nullptr, nullptr, nullptr,
                                             nullptr, nullptr, nullptr, nullptr);
  // 3) ux1,ux2 = embedded @ Uall{1,2}^T + (Uall_b + Wall_b), one launch
  k_gemm<4><<<dim3(200,16), 256, 0, stream>>>(embB, Uall1B, 1024, 256, ux1, nullptr,
                                              Uall1b, Wall1b,
                                              Uall2B, ux2, Uall2b, Wall2b,
                                              nullptr, nullptr);
  // 4) zero E + ctx + wave-flags (atomic/poll targets)
  k_init<<<229, 256, 0, stream>>>(E, ctx, fl);
  // 5) both TimeLSTM scans (32 persistent WGs, 2-way j-split, pairwise exchange)
  k_scan<<<32, 256, 0, stream>>>(Wall1B, Wd1B, Wd1b, ux1, h01, c01,
                                 Wall2B, Wd2B, Wd2b, ux2, h02, c02,
                                 tstamp, wa, E, out2, hx, cx, fl);
  // 6) alpha = softmax(E)
  k_attn<<<128, 256, 0, stream>>>(E, alpha);
  // 7) ctx += sum_s emb * tanh(out2 @ Wb^T) * alpha  (fused, no P buffer)
  k_gemm<5><<<dim3(200,2), 256, 0, stream>>>(out2, WbB, 256, 256, ctx, nullptr,
                                             nullptr, nullptr, nullptr, nullptr,
                                             nullptr, nullptr, embF, alpha);
  // 8) out = ctx @ Wout^T
  k_out<<<128, 128, 0, stream>>>(ctx, Woutw, (float*)d_out);
}

// Round 4
// 1072.821 us; speedup vs baseline: 1.4757x; 1.4757x over previous
//
#include <hip/hip_runtime.h>

typedef unsigned short u16;
typedef unsigned int u32;
typedef unsigned long long u64;
typedef __attribute__((ext_vector_type(8))) short bf16x8;
typedef __attribute__((ext_vector_type(4))) float f32x4;
typedef __attribute__((ext_vector_type(4))) unsigned short us4;

#define MFMA(a,b,c) __builtin_amdgcn_mfma_f32_16x16x32_bf16((a),(b),(c),0,0,0)
#define KEEP(x) asm volatile("" : "+v"(x))

// B=128, SEQ=200, VOCAB=1400 (pad 1408), D=H=256, 4H=1024, NCLS=128, M=B*SEQ=25600

static __device__ __forceinline__ u16 f2b(float f){
  unsigned u = __float_as_uint(f);
  u += 0x7fffu + ((u >> 16) & 1u);          // RNE fp32 -> bf16
  return (u16)(u >> 16);
}
static __device__ __forceinline__ float sigm(float x){ return 1.0f/(1.0f+__expf(-x)); }
static __device__ __forceinline__ float tanhx(float x){
  x = fminf(fmaxf(x, -15.f), 15.f);
  float e = __expf(-2.f*x);
  return (1.f - e)/(1.f + e);
}
static __device__ __forceinline__ void gl16(const void* g, void* l){
  __builtin_amdgcn_global_load_lds((const __attribute__((address_space(1))) void*)g,
                                   (__attribute__((address_space(3))) void*)l, 16, 0, 0);
}

// ---------------- fused prep: inputs cvt + emb transpose-cvt + weights ----
__global__ __launch_bounds__(256) void k_prep(
  const float* __restrict__ in0, u16* __restrict__ A0,
  const float* __restrict__ emb, u16* __restrict__ embT,
  const float* __restrict__ s0, const float* __restrict__ s1, const float* __restrict__ s2,
  const float* __restrict__ s3, const float* __restrict__ s4, const float* __restrict__ s5,
  const float* __restrict__ s6,
  u16* __restrict__ d0, u16* __restrict__ d1, u16* __restrict__ d2, u16* __restrict__ d3,
  u16* __restrict__ d4, u16* __restrict__ d5, u16* __restrict__ d6)
{
  int bx = blockIdx.x, tid = threadIdx.x;
  if (bx < 35200){                     // inputs [25600 x 1400] -> bf16 padded 1408
    long long i4 = (long long)bx*256 + tid;      // < 9011200 exactly
    long long o = i4*4;
    int r = (int)(o / 1408);
    int c = (int)(o % 1408);
    us4 d;
    if (c + 4 <= 1400){
      f32x4 v = *(const f32x4*)&in0[(long long)r*1400 + c];
      d[0]=f2b(v[0]); d[1]=f2b(v[1]); d[2]=f2b(v[2]); d[3]=f2b(v[3]);
    } else {
      for (int k=0;k<4;k++){ int cc=c+k; d[k] = (cc<1400)? f2b(in0[(long long)r*1400+cc]) : (u16)0; }
    }
    *(us4*)&A0[(long long)r*1408 + c] = d;
  } else if (bx < 36608){              // emb [1400x256] -> embT [256x1408] bf16
    int idx = (bx-35200)*256 + tid;    // < 360448 exactly
    int n = idx / 1408, k = idx % 1408;
    embT[idx] = (k < 1400) ? f2b(emb[(long long)k*256 + n]) : (u16)0;
  } else {                             // 7 weight arrays fp32 -> bf16
    long long q = (long long)(bx-36608)*256 + tid;   // < 311296 exactly
    const float* src; u16* dst; long long rel;
    if      (q < 65536)  { src=s0; dst=d0; rel=q; }
    else if (q < 131072) { src=s1; dst=d1; rel=q-65536; }
    else if (q < 196608) { src=s2; dst=d2; rel=q-131072; }
    else if (q < 262144) { src=s3; dst=d3; rel=q-196608; }
    else if (q < 278528) { src=s4; dst=d4; rel=q-262144; }
    else if (q < 294912) { src=s5; dst=d5; rel=q-278528; }
    else                 { src=s6; dst=d6; rel=q-294912; }
    long long o = rel*4;
    f32x4 v = *(const f32x4*)&src[o];
    us4 d; d[0]=f2b(v[0]); d[1]=f2b(v[1]); d[2]=f2b(v[2]); d[3]=f2b(v[3]);
    *(us4*)&dst[o] = d;
  }
}

// ---------------- init: zero E + ctx + wave-flags ------------------------
__global__ __launch_bounds__(256) void k_init(float* __restrict__ E, float* __restrict__ ctx,
                                              int* __restrict__ fl){
  int i = blockIdx.x*256 + threadIdx.x;     // 229*256 = 58624 exactly
  if (i < 25600) E[i] = 0.f;
  else if (i < 58368) ctx[i-25600] = 0.f;   // 32768
  else fl[i-58368] = 0;                     // 256 wave-flags (unsigned >= poll)
}

// ---------------- bf16 MFMA GEMM: C[M,N] = A[M,K] * Bt[N,K]^T -------------
// EPI 1: write fp32 + bf16 copies
// EPI 4: dual-output ux GEMM, +bias pair, fp32 (blockIdx.y>=8 -> second set)
// EPI 5: ctx[b,col] += emb[row,col]*tanh(acc)*alpha[row]  (LDS + global atomics)
template<int EPI>
__global__ __launch_bounds__(256) void k_gemm(const u16* __restrict__ A, const u16* __restrict__ Bt,
    int N, int K,
    float* __restrict__ Cf, u16* __restrict__ Cb,
    const float* __restrict__ bias1, const float* __restrict__ bias2,
    const u16* __restrict__ Bt2, float* __restrict__ Cf2,
    const float* __restrict__ bias3, const float* __restrict__ bias4,
    const float* __restrict__ emb, const float* __restrict__ alpha)
{
  __shared__ __align__(16) u16 As[128*64];
  __shared__ __align__(16) u16 Bs[128*64];
  __shared__ float red[2][128];
  const int tid = threadIdx.x;
  const int l = tid & 63, w = tid >> 6;
  const int quad = l >> 4, lb = l & 15;
  const int wr = w >> 1, wc = w & 1;
  const long long m0 = (long long)blockIdx.x * 128;
  int n0 = blockIdx.y * 128;
  if (EPI==4 && blockIdx.y >= 8){
    Bt = Bt2; Cf = Cf2; bias1 = bias3; bias2 = bias4; n0 = (blockIdx.y-8)*128;
  }

  f32x4 acc[4][4];
  #pragma unroll
  for (int i=0;i<4;i++)
    #pragma unroll
    for (int j=0;j<4;j++) acc[i][j] = (f32x4){0.f,0.f,0.f,0.f};

  for (int kk = 0; kk < K; kk += 64){
    #pragma unroll
    for (int it=0; it<4; ++it){      // 128x64 bf16 tile, XOR-swizzled 16B slots
      int slot = it*256 + tid;
      int m = slot >> 3;
      int q = (slot & 7) ^ (m & 7);
      gl16(A + (m0+m)*K + kk + q*8, &As[slot*8]);
    }
    #pragma unroll
    for (int it=0; it<4; ++it){
      int slot = it*256 + tid;
      int m = slot >> 3;
      int q = (slot & 7) ^ (m & 7);
      gl16(Bt + (long long)(n0+m)*K + kk + q*8, &Bs[slot*8]);
    }
    __syncthreads();
    #pragma unroll
    for (int ks=0; ks<2; ++ks){
      int kq = quad + ks*4;
      bf16x8 af[4], bfr[4];
      #pragma unroll
      for (int i=0;i<4;i++){ int m = wr*64 + i*16 + lb; af[i]  = *(const bf16x8*)&As[m*64 + ((kq ^ (m&7))*8)]; }
      #pragma unroll
      for (int j=0;j<4;j++){ int n = wc*64 + j*16 + lb; bfr[j] = *(const bf16x8*)&Bs[n*64 + ((kq ^ (n&7))*8)]; }
      #pragma unroll
      for (int i=0;i<4;i++)
        #pragma unroll
        for (int j=0;j<4;j++)
          acc[i][j] = MFMA(af[i], bfr[j], acc[i][j]);
    }
    __syncthreads();
  }

  if (EPI==5){
    const int b0 = (int)(m0 / 200);
    red[tid>>7][tid&127] = 0.f;
    __syncthreads();
    #pragma unroll
    for (int i=0;i<4;i++){
      #pragma unroll
      for (int j=0;j<4;j++){
        int col = wc*64 + j*16 + lb;          // 0..127 within n0 tile
        #pragma unroll
        for (int r=0;r<4;r++){
          long long row = m0 + wr*64 + i*16 + quad*4 + r;
          long long o = row*N + n0 + col;
          float v = emb[o] * tanhx(acc[i][j][r]) * alpha[row];
          atomicAdd(&red[(int)(row/200) - b0][col], v);
        }
      }
    }
    __syncthreads();
    int bl = tid >> 7, col = tid & 127;       // 256 threads cover [2][128]
    int bb = b0 + bl;
    if (bb < 128) atomicAdd(&Cf[bb*256 + n0 + col], red[bl][col]);
    return;
  }

  #pragma unroll
  for (int i=0;i<4;i++){
    #pragma unroll
    for (int j=0;j<4;j++){
      int col = n0 + wc*64 + j*16 + lb;
      #pragma unroll
      for (int r=0;r<4;r++){
        long long row = m0 + wr*64 + i*16 + quad*4 + r;
        long long o = row*N + col;
        float v = acc[i][j][r];
        if (EPI==1){ Cf[o]=v; Cb[o]=f2b(v); }
        else { Cf[o] = v + bias1[col] + bias2[col]; }   // EPI 4
      }
    }
  }
}

// ---------------- persistent TimeLSTM scan, weights in registers ----------
// r0 geometry (64 WGs: jw=bi>>4 j-quarter, grp=bi&15, lstm=(bi>>3)&1, bc=bi&7)
// + r2-proven per-wave flag protocol. All cross-WG traffic is agent-scope
// __hip_atomic (MALL-coherent, placement-independent).
//
// Per-step schedule (keeps slow vmem acks out of every wait point):
//  1. consume uxr; issue uxr/ts prefetch for s+1  (hides under GEMV+elem)
//  2. Wd GEMV + Wall GEMV (LDS), elementwise
//  3. mailbox: 2x packed u64 per lane -> wave-local s_waitcnt vmcnt(0)
//     (prefetch already landed; prev-step outputs acked 1.5 steps ago)
//     -> lane0 publishes THIS wave's flag = s+1  (data-before-flag per wave)
//  4. B1 raw s_barrier (orders step-s LDS reads vs overwrites; no vm drain)
//  5. own-quarter LDS writes
//  6. poll: lanes 0..2 spin on the 3 sibling wave flags (4B each, no sleep)
//  7. refill: 6x u64 agent loads (wave-w band of each sibling quarter)
//  8. outputs E/out2 for step s (acks ripen during next GEMV, off all drains)
//  9. unpack -> LDS, lgkmcnt(0), B2 raw s_barrier
// Flags monotonic 1..199 (k_init zeroes); unsigned >= poll is deadlock-free.
// Slot-parity double buffer + mutual-dependence induction => no overwrite.
__global__ __launch_bounds__(256,1) void k_scan(
  const u16* __restrict__ Wall1, const u16* __restrict__ Wd1, const float* __restrict__ Wd1b,
  const float* __restrict__ ux1, const float* __restrict__ h01, const float* __restrict__ c01,
  const u16* __restrict__ Wall2, const u16* __restrict__ Wd2, const float* __restrict__ Wd2b,
  const float* __restrict__ ux2, const float* __restrict__ h02, const float* __restrict__ c02,
  const float* __restrict__ ts, const float* __restrict__ wa,
  float* __restrict__ E, u16* __restrict__ out2,
  u64* __restrict__ mb, int* __restrict__ fl)
{
  __shared__ __align__(16) u16 hb[16][264];
  __shared__ __align__(16) u16 cb[16][264];
  const int bi = blockIdx.x;
  const int jw   = bi >> 4;
  const int grp  = bi & 15;
  const int lstm = (bi >> 3) & 1;
  const int bc   = bi & 7;
  const u16* Wall  = lstm ? Wall2 : Wall1;
  const u16* Wd    = lstm ? Wd2   : Wd1;
  const float* Wdb = lstm ? Wd2b  : Wd1b;
  const float* ux  = lstm ? ux2   : ux1;
  const float* h0  = lstm ? h02   : h01;
  const float* c0  = lstm ? c02   : c01;

  const int tid = threadIdx.x;
  const int l = tid & 63, w = tid >> 6;
  const int quad = l >> 4, lb = l & 15;
  const int bg = bc*16 + lb;            // lane's global batch
  const int jwave = jw*64 + w*16;       // wave's 16 output rows (per gate)
  const int jlane = jwave + quad*4;     // lane's 4 j rows (C-layout)

  // ---- one-time: weight fragments into registers (A-frag: m=lb, k=quad*8+i)
  bf16x8 wfA[4][8], wdA[8];
  #pragma unroll
  for (int g=0; g<4; ++g)
    #pragma unroll
    for (int kk=0; kk<8; ++kk){
      wfA[g][kk] = *(const bf16x8*)&Wall[(long long)(g*256 + jwave + lb)*256 + kk*32 + quad*8];
      KEEP(wfA[g][kk]);
    }
  #pragma unroll
  for (int kk=0; kk<8; ++kk){
    wdA[kk] = *(const bf16x8*)&Wd[(long long)(jwave + lb)*256 + kk*32 + quad*8];
    KEEP(wdA[kk]);
  }

  f32x4 bcs  = *(const f32x4*)&Wdb[jlane];
  f32x4 wav  = *(const f32x4*)&wa[jlane];
  f32x4 creg = *(const f32x4*)&c0[(long long)bg*256 + jlane];

  // ---- init LDS h/c (full 256 j for our 16 batches), bf16
  {
    const int bbi = tid >> 4, j0i = (tid & 15) * 16;
    #pragma unroll
    for (int kq=0; kq<4; ++kq){
      f32x4 hv = *(const f32x4*)&h0[(long long)(bc*16+bbi)*256 + j0i + kq*4];
      f32x4 cv = *(const f32x4*)&c0[(long long)(bc*16+bbi)*256 + j0i + kq*4];
      us4 hp0, cp0;
      #pragma unroll
      for (int r=0;r<4;++r){ hp0[r]=f2b(hv[r]); cp0[r]=f2b(cv[r]); }
      *(us4*)&hb[bbi][j0i+kq*4] = hp0;
      *(us4*)&cb[bbi][j0i+kq*4] = cp0;
    }
  }
  __syncthreads();

  f32x4 uxr[4];
  #pragma unroll
  for (int g=0; g<4; ++g)
    uxr[g] = *(const f32x4*)&ux[(long long)bg*200*1024 + g*256 + jlane];
  float tcur = ts[(long long)bg*200];

  for (int s=0; s<200; ++s){
    // 1) consume ux; immediately issue next step's prefetch (full-step hiding)
    f32x4 ag[4];
    #pragma unroll
    for (int g=0; g<4; ++g) ag[g] = uxr[g];
    float tnext = tcur;
    if (s < 199){
      #pragma unroll
      for (int g=0; g<4; ++g)
        uxr[g] = *(const f32x4*)&ux[((long long)bg*200 + s+1)*1024 + g*256 + jlane];
      tnext = ts[(long long)bg*200 + s+1];
    }
    // 2) c_s1 pre-act: Wd GEMV over cb
    f32x4 ad = bcs;
    #pragma unroll
    for (int kk=0;kk<8;++kk){
      bf16x8 cf = *(const bf16x8*)&cb[lb][kk*32 + quad*8];
      ad = MFMA(wdA[kk], cf, ad);
    }
    //    gates: Wall GEMV over hb
    #pragma unroll
    for (int kk=0;kk<8;++kk){
      bf16x8 hf = *(const bf16x8*)&hb[lb][kk*32 + quad*8];
      #pragma unroll
      for (int g=0; g<4; ++g) ag[g] = MFMA(wfA[g][kk], hf, ag[g]);
    }
    //    elementwise update (fp32 c carried in regs)
    f32x4 hn; us4 hp, cp;
    #pragma unroll
    for (int r=0;r<4;++r){
      float cs1 = tanhx(ad[r]);
      float cadj = creg[r] + cs1*(tcur - 1.0f);
      float fg = sigm(ag[0][r]);
      float ig = sigm(ag[1][r]);
      float og = sigm(ag[2][r]);
      float cg = sigm(ag[3][r]);
      float cn = fg*cadj + ig*cg;
      float hv = og*tanhx(cn);
      creg[r]=cn; hn[r]=hv;
      hp[r]=f2b(hv); cp[r]=f2b(cn);
    }

    if (s < 199){
      const int slot = (s+1)&1;
      // 3) mailbox stores (dense packed h|c), wave-local drain, flag publish
      {
        long long xb = ((long long)((((slot*16+grp)*4 + jw)*4 + w)))*128 + l*2;
        u64 w0 = (u64)((u32)hp[0] | ((u32)cp[0]<<16)) | ((u64)((u32)hp[1] | ((u32)cp[1]<<16))<<32);
        u64 w1 = (u64)((u32)hp[2] | ((u32)cp[2]<<16)) | ((u64)((u32)hp[3] | ((u32)cp[3]<<16))<<32);
        __hip_atomic_store(&mb[xb],   w0, __ATOMIC_RELAXED, __HIP_MEMORY_SCOPE_AGENT);
        __hip_atomic_store(&mb[xb+1], w1, __ATOMIC_RELAXED, __HIP_MEMORY_SCOPE_AGENT);
      }
      asm volatile("s_waitcnt vmcnt(0)" ::: "memory");
      if (l == 0)
        __hip_atomic_store(&fl[(grp*4 + jw)*4 + w], s+1, __ATOMIC_RELAXED, __HIP_MEMORY_SCOPE_AGENT);
      // 4) B1 raw barrier: all waves' step-s LDS reads are done (operands
      //    latched before elementwise); orders them vs writes below
      asm volatile("" ::: "memory");
      __builtin_amdgcn_s_barrier();
      asm volatile("" ::: "memory");
      // 5) own quarter: registers -> LDS
      *(us4*)&hb[lb][jlane] = hp;
      *(us4*)&cb[lb][jlane] = cp;
      // 6) poll the 3 sibling wave flags (lanes 0..2), tight spin
      {
        const u32 tgt = (u32)(s+1);
        const int sj = (jw + 1 + l) & 3;
        const int* fp = &fl[(grp*4 + sj)*4 + w];
        for (;;){
          u32 fv = tgt;
          if (l < 3) fv = (u32)__hip_atomic_load(fp, __ATOMIC_RELAXED, __HIP_MEMORY_SCOPE_AGENT);
          if (__all((int)(fv >= tgt))) break;
        }
      }
      // 7) refill: this wave's 16-j band of each sibling quarter (6x u64)
      u64 d0a, d0b, d1a, d1b, d2a, d2b;
      {
        const int j1 = (jw+1)&3, j2 = (jw+2)&3, j3 = (jw+3)&3;
        long long rb1 = ((long long)((((slot*16+grp)*4 + j1)*4 + w)))*128 + l*2;
        long long rb2 = ((long long)((((slot*16+grp)*4 + j2)*4 + w)))*128 + l*2;
        long long rb3 = ((long long)((((slot*16+grp)*4 + j3)*4 + w)))*128 + l*2;
        d0a = __hip_atomic_load(&mb[rb1],   __ATOMIC_RELAXED, __HIP_MEMORY_SCOPE_AGENT);
        d0b = __hip_atomic_load(&mb[rb1+1], __ATOMIC_RELAXED, __HIP_MEMORY_SCOPE_AGENT);
        d1a = __hip_atomic_load(&mb[rb2],   __ATOMIC_RELAXED, __HIP_MEMORY_SCOPE_AGENT);
        d1b = __hip_atomic_load(&mb[rb2+1], __ATOMIC_RELAXED, __HIP_MEMORY_SCOPE_AGENT);
        d2a = __hip_atomic_load(&mb[rb3],   __ATOMIC_RELAXED, __HIP_MEMORY_SCOPE_AGENT);
        d2b = __hip_atomic_load(&mb[rb3+1], __ATOMIC_RELAXED, __HIP_MEMORY_SCOPE_AGENT);
      }
      // 8) outputs for step s: issued here so their MALL acks ripen during
      //    the next GEMV and never sit in a drain or the poll's waits
      if (lstm==0){
        float e = hn[0]*wav[0] + hn[1]*wav[1] + hn[2]*wav[2] + hn[3]*wav[3];
        e += __shfl_xor(e, 16, 64);
        e += __shfl_xor(e, 32, 64);
        if (l < 16) atomicAdd(&E[(long long)bg*200 + s], e);
      } else {
        *(us4*)&out2[((long long)bg*200 + s)*256 + jlane] = hp;
      }
      // 9) unpack -> LDS, then B2 (lgkm only; vmem stays in flight)
      {
        const int j1 = (jw+1)&3, j2 = (jw+2)&3, j3 = (jw+3)&3;
        us4 hh, cc;
        u32 lo, hi;
        lo=(u32)d0a; hi=(u32)(d0a>>32); hh[0]=(u16)lo; cc[0]=(u16)(lo>>16); hh[1]=(u16)hi; cc[1]=(u16)(hi>>16);
        lo=(u32)d0b; hi=(u32)(d0b>>32); hh[2]=(u16)lo; cc[2]=(u16)(lo>>16); hh[3]=(u16)hi; cc[3]=(u16)(hi>>16);
        *(us4*)&hb[lb][j1*64 + w*16 + quad*4] = hh;
        *(us4*)&cb[lb][j1*64 + w*16 + quad*4] = cc;
        lo=(u32)d1a; hi=(u32)(d1a>>32); hh[0]=(u16)lo; cc[0]=(u16)(lo>>16); hh[1]=(u16)hi; cc[1]=(u16)(hi>>16);
        lo=(u32)d1b; hi=(u32)(d1b>>32); hh[2]=(u16)lo; cc[2]=(u16)(lo>>16); hh[3]=(u16)hi; cc[3]=(u16)(hi>>16);
        *(us4*)&hb[lb][j2*64 + w*16 + quad*4] = hh;
        *(us4*)&cb[lb][j2*64 + w*16 + quad*4] = cc;
        lo=(u32)d2a; hi=(u32)(d2a>>32); hh[0]=(u16)lo; cc[0]=(u16)(lo>>16); hh[1]=(u16)hi; cc[1]=(u16)(hi>>16);
        lo=(u32)d2b; hi=(u32)(d2b>>32); hh[2]=(u16)lo; cc[2]=(u16)(lo>>16); hh[3]=(u16)hi; cc[3]=(u16)(hi>>16);
        *(us4*)&hb[lb][j3*64 + w*16 + quad*4] = hh;
        *(us4*)&cb[lb][j3*64 + w*16 + quad*4] = cc;
      }
      asm volatile("s_waitcnt lgkmcnt(0)" ::: "memory");
      __builtin_amdgcn_sched_barrier(0);
      __builtin_amdgcn_s_barrier();
      asm volatile("" ::: "memory");
      tcur = tnext;
    } else {
      // final step: outputs only
      if (lstm==0){
        float e = hn[0]*wav[0] + hn[1]*wav[1] + hn[2]*wav[2] + hn[3]*wav[3];
        e += __shfl_xor(e, 16, 64);
        e += __shfl_xor(e, 32, 64);
        if (l < 16) atomicAdd(&E[(long long)bg*200 + s], e);
      } else {
        *(us4*)&out2[((long long)bg*200 + s)*256 + jlane] = hp;
      }
    }
  }
}

// ---------------- softmax over precomputed E -> alpha ----------------
__global__ __launch_bounds__(256) void k_attn(const float* __restrict__ E, float* __restrict__ alpha){
  __shared__ float buf[256];
  int b = blockIdx.x, tid = threadIdx.x;
  float Ev = (tid < 200) ? E[(long long)b*200 + tid] : -1e30f;
  buf[tid]=Ev; __syncthreads();
  for (int st=128; st>0; st>>=1){ if (tid<st) buf[tid]=fmaxf(buf[tid],buf[tid+st]); __syncthreads(); }
  float mx = buf[0]; __syncthreads();
  float e = (tid<200)? __expf(Ev-mx) : 0.f;
  buf[tid]=e; __syncthreads();
  for (int st=128; st>0; st>>=1){ if (tid<st) buf[tid]+=buf[tid+st]; __syncthreads(); }
  float sm = buf[0];
  if (tid<200) alpha[(long long)b*200+tid] = e/sm;
}

// ---------------- out = ctx @ Wout^T ----------------
__global__ __launch_bounds__(128) void k_out(const float* __restrict__ ctx, const float* __restrict__ Wout,
                                             float* __restrict__ out){
  __shared__ float cs[256];
  int b = blockIdx.x, t = threadIdx.x;
  cs[t] = ctx[b*256+t]; cs[t+128] = ctx[b*256+t+128];
  __syncthreads();
  const float* wr = Wout + (long long)t*256;
  float a0=0,a1=0,a2=0,a3=0;
  for (int j=0;j<256;j+=4){
    f32x4 v = *(const f32x4*)&wr[j];
    a0+=v[0]*cs[j]; a1+=v[1]*cs[j+1]; a2+=v[2]*cs[j+2]; a3+=v[3]*cs[j+3];
  }
  out[(long long)b*128 + t] = (a0+a1)+(a2+a3);
}

extern "C" void kernel_launch(void* const* d_in, const int* in_sizes, int n_in,
                              void* d_out, int out_size, void* d_ws, size_t ws_size,
                              hipStream_t stream)
{
  (void)in_sizes; (void)n_in; (void)out_size; (void)ws_size;
  const float* inputs = (const float*)d_in[0];
  const float* tstamp = (const float*)d_in[1];
  const float* emb    = (const float*)d_in[2];
  const float* Wall1w = (const float*)d_in[3];
  const float* Wall1b = (const float*)d_in[4];
  const float* Uall1w = (const float*)d_in[5];
  const float* Uall1b = (const float*)d_in[6];
  const float* Wd1w   = (const float*)d_in[7];
  const float* Wd1b   = (const float*)d_in[8];
  const float* Wall2w = (const float*)d_in[9];
  const float* Wall2b = (const float*)d_in[10];
  const float* Uall2w = (const float*)d_in[11];
  const float* Uall2b = (const float*)d_in[12];
  const float* Wd2w   = (const float*)d_in[13];
  const float* Wd2b   = (const float*)d_in[14];
  const float* wa     = (const float*)d_in[15];
  const float* Wbw    = (const float*)d_in[16];
  const float* Woutw  = (const float*)d_in[17];
  const float* h01    = (const float*)d_in[18];
  const float* c01    = (const float*)d_in[19];
  const float* h02    = (const float*)d_in[20];
  const float* c02    = (const float*)d_in[21];

  char* ws = (char*)d_ws;
  float* ux1   = (float*)(ws + 0);              // 104857600
  float* ux2   = (float*)(ws + 104857600LL);
  float* embF  = (float*)(ws + 209715200LL);    // 26214400
  u16*   embB  = (u16*)  (ws + 235929600LL);    // 13107200
  char*  scr   =          ws + 249036800LL;     // 72089600 region
  u16*   A0    = (u16*)scr;                     // 72089600 (dead after embed GEMM)
  u16*   out2  = (u16*)  (scr + 0);             // 13107200
  float* alpha = (float*)(scr + 39321600LL);    // 102400
  float* ctx   = (float*)(scr + 39424000LL);    // 131072
  float* E     = (float*)(scr + 39555072LL);    // 102400
  u64*   mb    = (u64*)  (scr + 39657472LL);    // 524288 (2 slot x 16 grp x 4 jw x 4 w x 64 lane x 16B)
  int*   fl    = (int*)  (scr + 40181760LL);    // 1024 (256 wave-flags)
  u16* embT    = (u16*)(ws + 321126400LL);      // 720896
  u16* Wall1B  = (u16*)(ws + 321847296LL);      // 524288
  u16* Wall2B  = (u16*)(ws + 322371584LL);
  u16* Uall1B  = (u16*)(ws + 322895872LL);
  u16* Uall2B  = (u16*)(ws + 323420160LL);
  u16* Wd1B    = (u16*)(ws + 323944448LL);      // 131072
  u16* Wd2B    = (u16*)(ws + 324075520LL);
  u16* WbB     = (u16*)(ws + 324206592LL);
  // total ws: ~324.3 MB (same layout envelope as passing rounds)

  // 1) all conversions (inputs, emb^T, 7 weights) in one launch
  k_prep<<<37824, 256, 0, stream>>>(inputs, A0, emb, embT,
                                    Wall1w, Wall2w, Uall1w, Uall2w, Wd1w, Wd2w, Wbw,
                                    Wall1B, Wall2B, Uall1B, Uall2B, Wd1B, Wd2B, WbB);
  // 2) embedded = inputs @ emb  (fp32 + bf16 copies)
  k_gemm<1><<<dim3(200,2), 256, 0, stream>>>(A0, embT, 256, 1408, embF, embB,
                                             nullptr, nullptr, nullptr, nullptr,
                                             nullptr, nullptr, nullptr, nullptr);
  // 3) ux1,ux2 = embedded @ Uall{1,2}^T + (Uall_b + Wall_b), one launch
  k_gemm<4><<<dim3(200,16), 256, 0, stream>>>(embB, Uall1B, 1024, 256, ux1, nullptr,
                                              Uall1b, Wall1b,
                                              Uall2B, ux2, Uall2b, Wall2b,
                                              nullptr, nullptr);
  // 4) zero E + ctx + wave-flags (atomic/poll targets)
  k_init<<<229, 256, 0, stream>>>(E, ctx, fl);
  // 5) both TimeLSTM scans (64 persistent WGs, per-wave flag protocol)
  k_scan<<<64, 256, 0, stream>>>(Wall1B, Wd1B, Wd1b, ux1, h01, c01,
                                 Wall2B, Wd2B, Wd2b, ux2, h02, c02,
                                 tstamp, wa, E, out2, mb, fl);
  // 6) alpha = softmax(E)
  k_attn<<<128, 256, 0, stream>>>(E, alpha);
  // 7) ctx += sum_s emb * tanh(out2 @ Wb^T) * alpha  (fused, no P buffer)
  k_gemm<5><<<dim3(200,2), 256, 0, stream>>>(out2, WbB, 256, 256, ctx, nullptr,
                                             nullptr, nullptr, nullptr, nullptr,
                                             nullptr, nullptr, embF, alpha);
  // 8) out = ctx @ Wout^T
  k_out<<<128, 128, 0, stream>>>(ctx, Woutw, (float*)d_out);
}